// Round 1
// baseline (17204.121 us; speedup 1.0000x reference)
//
#include <hip/hip_runtime.h>
#include <stdint.h>

// ---------------- constants ----------------
constexpr int kB  = 64;    // batch
constexpr int kT  = 512;   // seq len
constexpr int kHD = 512;   // per-direction hidden
constexpr int kC  = 16;    // classes
constexpr int kSTART = 14;
constexpr int kSTOP  = 15;
#define NEGV (-10000.0f)

typedef __bf16 bf16x8 __attribute__((ext_vector_type(8)));
typedef float  f32x4  __attribute__((ext_vector_type(4)));

union U16x8 { uint4 u; bf16x8 v; };

__device__ __forceinline__ unsigned short f2bf(float f) {
    union { float f; unsigned int u; } x; x.f = f;
    unsigned int u = x.u;
    u += 0x7fffu + ((u >> 16) & 1u);           // RNE
    return (unsigned short)(u >> 16);
}
__device__ __forceinline__ float bf2f(unsigned int hbits) {
    union { unsigned int u; float f; } x; x.u = hbits << 16;
    return x.f;
}

// ---------------- embedding gather: X0[t][b][e] = bf16(emb[sent[b][t]][e]) ----------------
__global__ void k_embed(const int* __restrict__ sent, const float* __restrict__ emb,
                        unsigned short* __restrict__ X0) {
    int row = blockIdx.x;              // t*64 + b
    int t = row >> 6, b = row & 63;
    int v = sent[b * kT + t];
    const float4* src = (const float4*)(emb + (size_t)v * 512);
    float4 f = src[threadIdx.x];       // block = 128 -> 512 floats
    ushort4 o;
    o.x = f2bf(f.x); o.y = f2bf(f.y); o.z = f2bf(f.z); o.w = f2bf(f.w);
    ((ushort4*)(X0 + (size_t)row * 512))[threadIdx.x] = o;
}

// ---------------- weight concat to bf16: wc[d][n][k] = k<din ? wih[d][n][k] : whh[d][n][k-din] ----------------
__global__ void k_wcat(const float* __restrict__ wih, const float* __restrict__ whh,
                       int din, unsigned short* __restrict__ wc) {
    int K = din + kHD;
    size_t gid = (size_t)blockIdx.x * blockDim.x + threadIdx.x;
    size_t e8 = gid * 8;
    size_t total = (size_t)2 * 2048 * K;
    if (e8 >= total) return;
    int k = (int)(e8 % K);
    size_t dn = e8 / K;                 // d*2048 + n
    const float* src = (k < din) ? (wih + dn * din + k) : (whh + dn * kHD + (k - din));
    float4 a = ((const float4*)src)[0];
    float4 b = ((const float4*)src)[1];
    ushort4 lo, hi;
    lo.x = f2bf(a.x); lo.y = f2bf(a.y); lo.z = f2bf(a.z); lo.w = f2bf(a.w);
    hi.x = f2bf(b.x); hi.y = f2bf(b.y); hi.z = f2bf(b.z); hi.w = f2bf(b.w);
    ushort4* dst = (ushort4*)(wc + e8);
    dst[0] = lo; dst[1] = hi;
}

// ---------------- init states (h parity-0 buffers, c) + fused biases ----------------
// hcur layout: [layer][parity][dir][B][HD] bf16 ; ccur: [layer][dir][B][HD] f32
__global__ void k_init(const float* __restrict__ h0, const float* __restrict__ c0,
                       const float* __restrict__ bih0, const float* __restrict__ bhh0,
                       const float* __restrict__ bih1, const float* __restrict__ bhh1,
                       unsigned short* __restrict__ hcur, float* __restrict__ ccur,
                       float* __restrict__ bias0, float* __restrict__ bias1) {
    int i = blockIdx.x * blockDim.x + threadIdx.x;
    const int NS = 4 * kB * kHD;       // 131072
    if (i < NS) {
        int l = i / (2 * kB * kHD);
        int rem = i % (2 * kB * kHD);
        hcur[(size_t)l * (4 * kB * kHD) + rem] = f2bf(h0[i]);  // parity 0
        ccur[i] = c0[i];
    } else if (i < NS + 4096) {
        int j = i - NS;  bias0[j] = bih0[j] + bhh0[j];
    } else if (i < NS + 8192) {
        int j = i - NS - 4096;  bias1[j] = bih1[j] + bhh1[j];
    }
}

// ---------------- one LSTM timestep, both directions ----------------
// grid = 64 wgs: d = blk>>5, hidden slice j0 = (blk&31)*16 ; block = 256 (4 waves = 4 gates)
// gates[m][n] = sum_k Z[m][k]*W[n][k],  Z = [x_t ; h_prev] (K = din+512), chunked by 256 in LDS
__launch_bounds__(256, 1)
__global__ void k_lstm_step(const unsigned short* __restrict__ W,   // [2][2048][K] bf16
                            const float* __restrict__ bias,          // [2][2048]
                            const unsigned short* __restrict__ Xin,  // [T][B][din] bf16
                            int din,
                            unsigned short* __restrict__ hcur,       // this layer: [2p][2d][B][HD]
                            float* __restrict__ ccur,                // this layer: [2d][B][HD]
                            unsigned short* __restrict__ out,        // [T][B][1024]
                            int s) {
    const int K   = din + kHD;
    const int nc  = K >> 8;            // 256-chunks
    const int nxc = din >> 8;
    const int d   = blockIdx.x >> 5;
    const int j0  = (blockIdx.x & 31) << 4;
    const int t   = d ? (kT - 1 - s) : s;
    const int tid  = threadIdx.x;
    const int wave = tid >> 6;         // gate type: 0=i 1=f 2=g 3=o
    const int lane = tid & 63;
    const int l16  = lane & 15;
    const int quad = lane >> 4;

    __shared__ unsigned short zbuf[64 * 264];      // 256-chunk of Z, +8 pad
    __shared__ float gstash[4][64][16];

    f32x4 acc0 = {0,0,0,0}, acc1 = {0,0,0,0}, acc2 = {0,0,0,0}, acc3 = {0,0,0,0};

    const unsigned short* hread = hcur + ((size_t)((s & 1) * 2 + d)) * (kB * kHD);
    const unsigned short* xbase = Xin + (size_t)t * kB * din;
    const unsigned short* wrow  = W + ((size_t)(d * 2048 + wave * 512 + j0 + l16)) * K + quad * 8;

    const int r = tid >> 2;            // staging row (batch) 0..63
    const int q = tid & 3;             // quarter of 256-wide chunk

    for (int c = 0; c < nc; ++c) {
        __syncthreads();
        {
            const unsigned short* src = (c < nxc) ? (xbase + (size_t)r * din + c * 256)
                                                  : (hread + (size_t)r * kHD + (c - nxc) * 256);
            const uint4* s4 = (const uint4*)(src + q * 64);
            uint4* dl = (uint4*)(zbuf + r * 264 + q * 64);
            #pragma unroll
            for (int i = 0; i < 8; ++i) dl[i] = s4[i];
        }
        __syncthreads();
        const unsigned short* wc = wrow + c * 256;
        #pragma unroll
        for (int kk = 0; kk < 8; ++kk) {
            U16x8 bfr; bfr.u = *(const uint4*)(wc + kk * 32);
            const unsigned short* zb = zbuf + kk * 32 + quad * 8;
            U16x8 a0, a1, a2, a3;
            a0.u = *(const uint4*)(zb + (size_t)(l16) * 264);
            a1.u = *(const uint4*)(zb + (size_t)(16 + l16) * 264);
            a2.u = *(const uint4*)(zb + (size_t)(32 + l16) * 264);
            a3.u = *(const uint4*)(zb + (size_t)(48 + l16) * 264);
            acc0 = __builtin_amdgcn_mfma_f32_16x16x32_bf16(a0.v, bfr.v, acc0, 0, 0, 0);
            acc1 = __builtin_amdgcn_mfma_f32_16x16x32_bf16(a1.v, bfr.v, acc1, 0, 0, 0);
            acc2 = __builtin_amdgcn_mfma_f32_16x16x32_bf16(a2.v, bfr.v, acc2, 0, 0, 0);
            acc3 = __builtin_amdgcn_mfma_f32_16x16x32_bf16(a3.v, bfr.v, acc3, 0, 0, 0);
        }
    }
    // C/D layout (verified m89): col = lane&15 (=n/j), row = quad*4+reg (=m within 16-subtile)
    {
        int rb = quad * 4;
        #pragma unroll
        for (int rr = 0; rr < 4; ++rr) {
            gstash[wave][ 0 + rb + rr][l16] = acc0[rr];
            gstash[wave][16 + rb + rr][l16] = acc1[rr];
            gstash[wave][32 + rb + rr][l16] = acc2[rr];
            gstash[wave][48 + rb + rr][l16] = acc3[rr];
        }
    }
    __syncthreads();
    // cell update: 64x16 elements, 4 per thread
    {
        unsigned short* hwrite = hcur + ((size_t)(((s + 1) & 1) * 2 + d)) * (kB * kHD);
        int m  = tid >> 2;
        int jq = (tid & 3) * 4;
        const float* bi = bias + d * 2048;
        #pragma unroll
        for (int e = 0; e < 4; ++e) {
            int j = jq + e;
            float gi = gstash[0][m][j] + bi[0 * 512 + j0 + j];
            float gf = gstash[1][m][j] + bi[1 * 512 + j0 + j];
            float gg = gstash[2][m][j] + bi[2 * 512 + j0 + j];
            float go = gstash[3][m][j] + bi[3 * 512 + j0 + j];
            float si = 1.f / (1.f + __expf(-gi));
            float sf = 1.f / (1.f + __expf(-gf));
            float so = 1.f / (1.f + __expf(-go));
            float tg = tanhf(gg);
            size_t ci = (size_t)d * (kB * kHD) + (size_t)m * kHD + j0 + j;
            float cn = sf * ccur[ci] + si * tg;
            ccur[ci] = cn;
            float hn = so * tanhf(cn);
            unsigned short hb = f2bf(hn);
            hwrite[(size_t)m * kHD + j0 + j] = hb;
            out[(size_t)t * (kB * 1024) + (size_t)m * 1024 + d * kHD + j0 + j] = hb;
        }
    }
}

// ---------------- final linear: feats[b][t][c] = hs1[t][b][:] . lw[c][:] + lb[c] ----------------
__global__ void k_linear(const unsigned short* __restrict__ hs1,
                         const float* __restrict__ lw, const float* __restrict__ lb,
                         float* __restrict__ feats) {
    int p = blockIdx.x * 4 + (threadIdx.x >> 6);   // row = t*64+b
    int lane = threadIdx.x & 63;
    const unsigned short* row = hs1 + (size_t)p * 1024 + lane * 16;
    uint4 u0 = ((const uint4*)row)[0];
    uint4 u1 = ((const uint4*)row)[1];
    unsigned int uu[8] = {u0.x, u0.y, u0.z, u0.w, u1.x, u1.y, u1.z, u1.w};
    float x[16];
    #pragma unroll
    for (int i = 0; i < 8; ++i) { x[2*i] = bf2f(uu[i] & 0xffffu); x[2*i+1] = bf2f(uu[i] >> 16); }
    float acc[16];
    #pragma unroll
    for (int c = 0; c < 16; ++c) {
        const float4* w4 = (const float4*)(lw + (size_t)c * 1024 + lane * 16);
        float a = 0.f;
        #pragma unroll
        for (int k4 = 0; k4 < 4; ++k4) {
            float4 w = w4[k4];
            a += x[k4*4+0]*w.x + x[k4*4+1]*w.y + x[k4*4+2]*w.z + x[k4*4+3]*w.w;
        }
        acc[c] = a;
    }
    #pragma unroll
    for (int c = 0; c < 16; ++c) {
        #pragma unroll
        for (int off = 32; off; off >>= 1) acc[c] += __shfl_xor(acc[c], off, 64);
    }
    if (lane == 0) {
        int t = p >> 6, b = p & 63;
        float* o = feats + (size_t)b * (kT * kC) + t * kC;
        #pragma unroll
        for (int c = 0; c < 16; ++c) o[c] = acc[c] + lb[c];
    }
}

// ---------------- Viterbi: one wave per batch element ----------------
__global__ void k_viterbi(const float* __restrict__ feats, const float* __restrict__ trans,
                          float* __restrict__ out) {
    int b = blockIdx.x;
    int lane = threadIdx.x;            // block = 64
    __shared__ unsigned char bp[kT * kC];
    __shared__ float fv[2][kC];
    __shared__ float tbuf[kC];
    float trow[16];
    float tstop = 0.f;
    if (lane < 16) {
        #pragma unroll
        for (int p = 0; p < 16; ++p) trow[p] = trans[lane * 16 + p];
        tstop = trans[kSTOP * 16 + lane];
        fv[0][lane] = (lane == kSTART) ? 0.f : NEGV;
    }
    __syncthreads();
    const float* fb = feats + (size_t)b * (kT * kC);
    for (int t = 0; t < kT; ++t) {
        if (lane < 16) {
            float m = -3.4e38f; int arg = 0;
            #pragma unroll
            for (int p = 0; p < 16; ++p) {
                float v = fv[t & 1][p] + trow[p];
                if (v > m) { m = v; arg = p; }   // strict > : first max, matches jnp.argmax
            }
            bp[t * 16 + lane] = (unsigned char)arg;
            fv[(t + 1) & 1][lane] = m + fb[t * 16 + lane];
        }
        __syncthreads();
    }
    if (lane < 16) tbuf[lane] = fv[kT & 1][lane] + tstop;
    __syncthreads();
    if (lane == 0) {
        float bm = tbuf[0]; int best = 0;
        #pragma unroll
        for (int p = 1; p < 16; ++p) if (tbuf[p] > bm) { bm = tbuf[p]; best = p; }
        out[b] = bm;
        float* path = out + kB + (size_t)b * kT;
        int tag = best;
        for (int t = kT - 1; t >= 0; --t) {
            path[t] = (float)tag;
            tag = bp[t * 16 + tag];
        }
    }
}

// ---------------- host ----------------
extern "C" void kernel_launch(void* const* d_in, const int* in_sizes, int n_in,
                              void* d_out, int out_size, void* d_ws, size_t ws_size,
                              hipStream_t stream) {
    const int*   sent = (const int*)d_in[0];
    const float* emb  = (const float*)d_in[1];
    const float* wih0 = (const float*)d_in[2];
    const float* whh0 = (const float*)d_in[3];
    const float* bih0 = (const float*)d_in[4];
    const float* bhh0 = (const float*)d_in[5];
    const float* wih1 = (const float*)d_in[6];
    const float* whh1 = (const float*)d_in[7];
    const float* bih1 = (const float*)d_in[8];
    const float* bhh1 = (const float*)d_in[9];
    const float* lw   = (const float*)d_in[10];
    const float* lb   = (const float*)d_in[11];
    const float* tr   = (const float*)d_in[12];
    const float* h0   = (const float*)d_in[13];
    const float* c0   = (const float*)d_in[14];
    float* out = (float*)d_out;

    char* ws = (char*)d_ws;
    size_t off = 0;
    auto alloc = [&](size_t bytes) -> void* {
        void* p = ws + off; off += (bytes + 255) & ~(size_t)255; return p;
    };
    unsigned short* Wc0   = (unsigned short*)alloc((size_t)2 * 2048 * 1024 * 2);
    unsigned short* Wc1   = (unsigned short*)alloc((size_t)2 * 2048 * 1536 * 2);
    float*          bias0 = (float*)alloc(4096 * 4);
    float*          bias1 = (float*)alloc(4096 * 4);
    unsigned short* X0    = (unsigned short*)alloc((size_t)kT * kB * 512 * 2);
    unsigned short* hs0   = (unsigned short*)alloc((size_t)kT * kB * 1024 * 2);
    unsigned short* hs1   = (unsigned short*)alloc((size_t)kT * kB * 1024 * 2);
    unsigned short* hcur  = (unsigned short*)alloc((size_t)2 * 2 * 2 * kB * kHD * 2); // [l][p][d][B][HD]
    float*          ccur  = (float*)alloc((size_t)4 * kB * kHD * 4);                   // [l][d][B][HD]
    float*          feats = (float*)alloc((size_t)kB * kT * kC * 4);

    k_wcat<<<(2 * 2048 * 1024 / 8 + 255) / 256, 256, 0, stream>>>(wih0, whh0, 512, Wc0);
    k_wcat<<<(2 * 2048 * 1536 / 8 + 255) / 256, 256, 0, stream>>>(wih1, whh1, 1024, Wc1);
    k_init<<<(4 * kB * kHD + 8192 + 255) / 256, 256, 0, stream>>>(h0, c0, bih0, bhh0, bih1, bhh1,
                                                                  hcur, ccur, bias0, bias1);
    k_embed<<<kT * kB, 128, 0, stream>>>(sent, emb, X0);

    unsigned short* hcur_l1 = hcur + (size_t)4 * kB * kHD;
    float*          ccur_l1 = ccur + (size_t)2 * kB * kHD;
    for (int s = 0; s < kT; ++s)
        k_lstm_step<<<64, 256, 0, stream>>>(Wc0, bias0, X0, 512, hcur, ccur, hs0, s);
    for (int s = 0; s < kT; ++s)
        k_lstm_step<<<64, 256, 0, stream>>>(Wc1, bias1, hs0, 1024, hcur_l1, ccur_l1, hs1, s);

    k_linear<<<kT * kB / 4, 256, 0, stream>>>(hs1, lw, lb, feats);
    k_viterbi<<<kB, 64, 0, stream>>>(feats, tr, out);
}